// Round 1
// baseline (231.473 us; speedup 1.0000x reference)
//
#include <hip/hip_runtime.h>

// Crop: out[i, j] = audio[i, j]            for j <  starts[i]
//       out[i, j] = audio[i, j + CROP_NUM] for j >= starts[i]
// B=128, L=262144, CROP_NUM=26214, OUT_LEN=235930.
// Traffic floor: 121 MB read + 121 MB write => ~38 us @6.3 TB/s.
// Harness fixed cost per iter ~142 us (512MB ws poison + 121MB out poison +
// 134MB d2d restore); kernel residual was ~70 us.
//
// R5: (a) loads are now CACHED (no nt) -- the previous nt v2f pair read only
//     8 of every 16 bytes per instruction with no-allocate, plausibly
//     double-fetching every 64B line from HBM; (b) 16B loads via memcpy with
//     8B alignment assumption (col and CROP are both even -> src always 8B
//     aligned; dwordx4 @ align-8 is legal on gfx950); (c) 8 floats/thread
//     halves addressing math and workgroup count. Stores stay non-temporal:
//     dense, 32B-aligned, no reuse.

constexpr int B_ = 128;
constexpr int L_ = 262144;
constexpr int CROP_ = 26214;
constexpr int OUT_LEN_ = L_ - CROP_;                     // 235930
constexpr unsigned TOTAL_ = (unsigned)B_ * OUT_LEN_;     // 30,199,040 (div by 8)
constexpr unsigned NGROUPS8_ = TOTAL_ / 8u;              // 3,774,880

typedef float v4f __attribute__((ext_vector_type(4)));

__global__ __launch_bounds__(256) void crop_kernel(const float* __restrict__ audio,
                                                   const int* __restrict__ starts,
                                                   float* __restrict__ out) {
    unsigned t = blockIdx.x * 256u + threadIdx.x;
    unsigned base = t * 8u;
    if (base >= TOTAL_) return;

    unsigned row = base / (unsigned)OUT_LEN_;            // magic-mul
    unsigned col = base - row * (unsigned)OUT_LEN_;

    v4f v0, v1;
    if (col + 8u <= (unsigned)OUT_LEN_) {
        int s = starts[row];                             // wave-mostly-uniform
        const float* src = audio + (size_t)row * L_ + col;
        bool straddle = ((int)col < s) & ((int)col + 8 > s);
        if (!straddle) {
            // Contiguous 32B from one side of the crop point; 8B-aligned
            // always (col even, CROP even). Cached loads: each 64B line is
            // fetched once and the overlapping halves hit L1.
            const float* p = (const float*)__builtin_assume_aligned(
                src + ((int)col >= s ? CROP_ : 0), 8);
            __builtin_memcpy(&v0, p, 16);
            __builtin_memcpy(&v1, p + 4, 16);
        } else {
            // starts[row] inside this group: <=1 group per row in whole grid.
            float tmp[8];
#pragma unroll
            for (int k = 0; k < 8; ++k) {
                int c = (int)col + k;
                tmp[k] = src[k + (c >= s ? CROP_ : 0)];
            }
            __builtin_memcpy(&v0, tmp, 16);
            __builtin_memcpy(&v1, tmp + 4, 16);
        }
    } else {
        // Group straddles a row boundary (<=127 groups total).
        float tmp[8];
#pragma unroll
        for (int k = 0; k < 8; ++k) {
            unsigned f = base + k;
            unsigned rw = f / (unsigned)OUT_LEN_;
            int c = (int)(f - rw * (unsigned)OUT_LEN_);
            int s = starts[rw];
            tmp[k] = audio[(size_t)rw * L_ + c + (c >= s ? CROP_ : 0)];
        }
        __builtin_memcpy(&v0, tmp, 16);
        __builtin_memcpy(&v1, tmp + 4, 16);
    }
    // 32B-aligned non-temporal stores (dense, streaming, no reuse).
    v4f* o = reinterpret_cast<v4f*>(out + base);
    __builtin_nontemporal_store(v0, o);
    __builtin_nontemporal_store(v1, o + 1);
}

extern "C" void kernel_launch(void* const* d_in, const int* in_sizes, int n_in,
                              void* d_out, int out_size, void* d_ws, size_t ws_size,
                              hipStream_t stream) {
    const float* audio = (const float*)d_in[0];
    const int* starts  = (const int*)d_in[1];
    float* out = (float*)d_out;

    int block = 256;
    int grid = (int)((NGROUPS8_ + (unsigned)block - 1) / (unsigned)block);  // 14746
    crop_kernel<<<grid, block, 0, stream>>>(audio, starts, out);
}

// Round 2
// 220.035 us; speedup vs baseline: 1.0520x; 1.0520x over previous
//
#include <hip/hip_runtime.h>

// Crop: out[i, j] = audio[i, j]            for j <  starts[i]
//       out[i, j] = audio[i, j + CROP_NUM] for j >= starts[i]
// B=128, L=262144, CROP_NUM=26214, OUT_LEN=235930.
// Traffic floor: 121 MB read + 121 MB write => ~38.5 us @6.3 TB/s.
// Harness fixed cost per iter ~142 us (512MB ws poison + 121MB out poison +
// 134MB d2d restore).
//
// R6 post-mortem of R5 (231us, regression): 8 floats/thread made the NT
// stores HALF-DENSE (2x16B at stride 32/lane) -> partial-line NT writes to
// HBM. Reverted to 4 floats/thread: one fully-dense 16B-aligned NT store
// per lane (wave = contiguous 1KB).
// Load path (the only change vs R4's 214us): single CACHED 16B load via
// memcpy align-8 (src always 8B-aligned: col and CROP both even), replacing
// R4's two half-dense NT v2f loads which plausibly double-fetched each 64B
// line under no-allocate.

constexpr int B_ = 128;
constexpr int L_ = 262144;
constexpr int CROP_ = 26214;
constexpr int OUT_LEN_ = L_ - CROP_;                     // 235930
constexpr unsigned TOTAL_ = (unsigned)B_ * OUT_LEN_;     // 30,199,040 (div by 4)
constexpr unsigned NGROUPS_ = TOTAL_ / 4u;               // 7,549,760

typedef float v4f __attribute__((ext_vector_type(4)));

__global__ __launch_bounds__(256) void crop_kernel(const float* __restrict__ audio,
                                                   const int* __restrict__ starts,
                                                   float* __restrict__ out) {
    unsigned t = blockIdx.x * 256u + threadIdx.x;
    unsigned base = t * 4u;
    if (base >= TOTAL_) return;

    unsigned row = base / (unsigned)OUT_LEN_;            // magic-mul
    unsigned col = base - row * (unsigned)OUT_LEN_;

    v4f v;
    if (col + 4u <= (unsigned)OUT_LEN_) {
        int s = starts[row];                             // wave-mostly-uniform
        const float* src = audio + (size_t)row * L_ + col;
        bool straddle = ((int)col < s) & ((int)col + 4 > s);
        if (!straddle) {
            // Contiguous 16B from one side of the crop point; 8B-aligned
            // always (col even, CROP even). Cached load: each 64B line
            // fetched once; split/boundary halves hit L1/L2.
            const float* p = (const float*)__builtin_assume_aligned(
                src + ((int)col >= s ? CROP_ : 0), 8);
            __builtin_memcpy(&v, p, 16);
        } else {
            // starts[row] inside this group: <=1 group per row in whole grid.
#pragma unroll
            for (int k = 0; k < 4; ++k) {
                int c = (int)col + k;
                v[k] = src[k + (c >= s ? CROP_ : 0)];
            }
        }
    } else {
        // Group straddles a row boundary (<=127 groups total).
#pragma unroll
        for (int k = 0; k < 4; ++k) {
            unsigned f = base + k;
            unsigned rw = f / (unsigned)OUT_LEN_;
            int c = (int)(f - rw * (unsigned)OUT_LEN_);
            int s = starts[rw];
            v[k] = audio[(size_t)rw * L_ + c + (c >= s ? CROP_ : 0)];
        }
    }
    // Fully dense, 16B-aligned non-temporal store (wave = contiguous 1KB).
    __builtin_nontemporal_store(v, reinterpret_cast<v4f*>(out + base));
}

extern "C" void kernel_launch(void* const* d_in, const int* in_sizes, int n_in,
                              void* d_out, int out_size, void* d_ws, size_t ws_size,
                              hipStream_t stream) {
    const float* audio = (const float*)d_in[0];
    const int* starts  = (const int*)d_in[1];
    float* out = (float*)d_out;

    int block = 256;
    int grid = (int)((NGROUPS_ + (unsigned)block - 1) / (unsigned)block);  // 29492
    crop_kernel<<<grid, block, 0, stream>>>(audio, starts, out);
}